// Round 1
// baseline (771.386 us; speedup 1.0000x reference)
//
#include <hip/hip_runtime.h>
#include <math.h>

#define NB 8
#define NN 1024
#define NC 128
#define INV_TAU (1.0f/0.3f)

__device__ __forceinline__ float wsum(float v){
  #pragma unroll
  for (int o = 32; o > 0; o >>= 1) v += __shfl_xor(v, o, 64);
  return v;
}
__device__ __forceinline__ float wmax(float v){
  #pragma unroll
  for (int o = 32; o > 0; o >>= 1) v = fmaxf(v, __shfl_xor(v, o, 64));
  return v;
}

// ---- zero accumulators + sinkhorn potentials (ws is poisoned 0xAA each run)
__global__ void k_init(float* accs, float* u, float* v){
  int i = blockIdx.x * 256 + threadIdx.x;   // grid 32 x 256 = 8192
  if (i < 64) accs[i] = 0.0f;
  u[i] = 0.0f; v[i] = 0.0f;
}

// ---- L2 normalize * 20 over C; feats[16,1024,128] -> f1 = rows 0::2, f2 = 1::2
__global__ void k_normalize(const float* __restrict__ feats,
                            float* __restrict__ f1, float* __restrict__ f2){
  int vid = blockIdx.x;            // 0..16383 = batch*1024+n
  int lane = threadIdx.x;          // 64 threads, 2 floats each
  const float* src = feats + (size_t)vid * NC;
  float2 x = *(const float2*)(src + lane * 2);
  float s = wsum(x.x * x.x + x.y * x.y);
  float sc = 20.0f / fmaxf(sqrtf(s), 1e-12f);
  int batch = vid >> 10, n = vid & 1023;
  float* dst = ((batch & 1) ? f2 : f1) + ((size_t)(batch >> 1) * NN + n) * NC;
  float2 y; y.x = x.x * sc; y.y = x.y * sc;
  *(float2*)(dst + lane * 2) = y;
}

// ---- C[b] = A[b] (1024x128) * B[(b+rollB)&7]^T -> [1024x1024]
__global__ __launch_bounds__(256) void k_gemm_bt(const float* __restrict__ A,
                                                 const float* __restrict__ Bm,
                                                 float* __restrict__ Cm, int rollB){
  __shared__ float As[64][68];   // [k][row], padded
  __shared__ float Bs[64][68];
  int b = blockIdx.z;
  int n0 = blockIdx.y * 64, m0 = blockIdx.x * 64;
  const float* Ab = A  + (size_t)b * NN * NC;
  const float* Bb = Bm + (size_t)((b + rollB) & 7) * NN * NC;
  float* Cb = Cm + (size_t)b * NN * NN;
  int tid = threadIdx.x;
  int ty = tid >> 4, tx = tid & 15;
  float acc[4][4] = {};
  for (int kk = 0; kk < NC; kk += 64){
    #pragma unroll
    for (int i = 0; i < 4; i++){
      int t = tid + 256 * i;          // 1024 float4 slots
      int r = t >> 4, k4 = t & 15;
      float4 va = *(const float4*)(Ab + (size_t)(n0 + r) * NC + kk + k4 * 4);
      As[k4*4+0][r] = va.x; As[k4*4+1][r] = va.y; As[k4*4+2][r] = va.z; As[k4*4+3][r] = va.w;
      float4 vb = *(const float4*)(Bb + (size_t)(m0 + r) * NC + kk + k4 * 4);
      Bs[k4*4+0][r] = vb.x; Bs[k4*4+1][r] = vb.y; Bs[k4*4+2][r] = vb.z; Bs[k4*4+3][r] = vb.w;
    }
    __syncthreads();
    #pragma unroll 8
    for (int k = 0; k < 64; k++){
      float4 a4 = *(const float4*)&As[k][ty * 4];
      float4 b4 = *(const float4*)&Bs[k][tx * 4];
      acc[0][0] += a4.x*b4.x; acc[0][1] += a4.x*b4.y; acc[0][2] += a4.x*b4.z; acc[0][3] += a4.x*b4.w;
      acc[1][0] += a4.y*b4.x; acc[1][1] += a4.y*b4.y; acc[1][2] += a4.y*b4.z; acc[1][3] += a4.y*b4.w;
      acc[2][0] += a4.z*b4.x; acc[2][1] += a4.z*b4.y; acc[2][2] += a4.z*b4.z; acc[2][3] += a4.z*b4.w;
      acc[3][0] += a4.w*b4.x; acc[3][1] += a4.w*b4.y; acc[3][2] += a4.w*b4.z; acc[3][3] += a4.w*b4.w;
    }
    __syncthreads();
  }
  #pragma unroll
  for (int i = 0; i < 4; i++){
    float4 o = make_float4(acc[i][0], acc[i][1], acc[i][2], acc[i][3]);
    *(float4*)(Cb + (size_t)(n0 + ty * 4 + i) * NN + m0 + tx * 4) = o;
  }
}

// ---- per-row logsumexp (softmax stats): lse = max + log(sum exp(x-max))
__global__ void k_rowstats(const float* __restrict__ Mb, float* __restrict__ lse){
  int row = blockIdx.x * 4 + (threadIdx.x >> 6);
  int lane = threadIdx.x & 63;
  const float* p = Mb + (size_t)row * NN;
  float x[16]; float mx = -3.402823466e38f;
  #pragma unroll
  for (int k = 0; k < 16; k++){ x[k] = p[lane + 64 * k]; mx = fmaxf(mx, x[k]); }
  mx = wmax(mx);
  float s = 0.0f;
  #pragma unroll
  for (int k = 0; k < 16; k++) s += expf(x[k] - mx);
  s = wsum(s);
  if (lane == 0) lse[row] = mx + logf(s);
}

// ---- row stats + argmax (first max wins) + correct_match count
__global__ void k_rowstats_argmax(const float* __restrict__ Mb, float* __restrict__ lse,
                                  float* __restrict__ accs){
  int row = blockIdx.x * 4 + (threadIdx.x >> 6);
  int lane = threadIdx.x & 63;
  const float* p = Mb + (size_t)row * NN;
  float x[16]; float mx = -3.402823466e38f;
  float bm = -3.402823466e38f; int bi = 0;
  #pragma unroll
  for (int k = 0; k < 16; k++){
    x[k] = p[lane + 64 * k];
    mx = fmaxf(mx, x[k]);
    if (x[k] > bm){ bm = x[k]; bi = lane + 64 * k; }
  }
  mx = wmax(mx);
  #pragma unroll
  for (int o = 32; o > 0; o >>= 1){
    float om = __shfl_xor(bm, o, 64); int oi = __shfl_xor(bi, o, 64);
    if (om > bm || (om == bm && oi < bi)){ bm = om; bi = oi; }
  }
  float s = 0.0f;
  #pragma unroll
  for (int k = 0; k < 16; k++) s += expf(x[k] - mx);
  s = wsum(s);
  if (lane == 0){
    lse[row] = mx + logf(s);
    if (bi == (row & 1023)) atomicAdd(&accs[48 + (blockIdx.x & 15)], 1.0f);
  }
}

// ---- fva[b,n,c] = sum_m exp(M[b,n,m]-lse1[b,n]) * f1[(b+1)&7][m][c]
__global__ __launch_bounds__(256) void k_fva(const float* __restrict__ Mb,
                                             const float* __restrict__ lse1,
                                             const float* __restrict__ f1,
                                             float* __restrict__ fva){
  __shared__ float Ps[64][36];    // [m][row(n)], 32 rows
  __shared__ float Bs[64][128];   // [m][c]
  int b = blockIdx.y;
  int n0 = blockIdx.x * 32;
  const float* Mrow = Mb + (size_t)(b * NN + n0) * NN;
  const float* fa = f1 + (size_t)((b + 1) & 7) * NN * NC;
  const float* lseb = lse1 + b * NN + n0;
  int tid = threadIdx.x;
  int ty = tid >> 5, tx = tid & 31;
  float acc[4][4] = {};
  for (int mm = 0; mm < NN; mm += 64){
    #pragma unroll
    for (int i = 0; i < 2; i++){
      int t = tid + 256 * i;        // 512 float4 = 32 rows x 64 m
      int r = t >> 4, m4 = t & 15;
      float l = lseb[r];
      float4 v = *(const float4*)(Mrow + (size_t)r * NN + mm + m4 * 4);
      Ps[m4*4+0][r] = expf(v.x - l); Ps[m4*4+1][r] = expf(v.y - l);
      Ps[m4*4+2][r] = expf(v.z - l); Ps[m4*4+3][r] = expf(v.w - l);
    }
    #pragma unroll
    for (int i = 0; i < 8; i++){
      int t = tid + 256 * i;        // 2048 float4 = 64 m x 128 c
      int m = t >> 5, c4 = t & 31;
      *(float4*)&Bs[m][c4 * 4] = *(const float4*)(fa + (size_t)(mm + m) * NC + c4 * 4);
    }
    __syncthreads();
    #pragma unroll 8
    for (int m = 0; m < 64; m++){
      float4 a4 = *(const float4*)&Ps[m][ty * 4];
      float4 b4 = *(const float4*)&Bs[m][tx * 4];
      acc[0][0] += a4.x*b4.x; acc[0][1] += a4.x*b4.y; acc[0][2] += a4.x*b4.z; acc[0][3] += a4.x*b4.w;
      acc[1][0] += a4.y*b4.x; acc[1][1] += a4.y*b4.y; acc[1][2] += a4.y*b4.z; acc[1][3] += a4.y*b4.w;
      acc[2][0] += a4.z*b4.x; acc[2][1] += a4.z*b4.y; acc[2][2] += a4.z*b4.z; acc[2][3] += a4.z*b4.w;
      acc[3][0] += a4.w*b4.x; acc[3][1] += a4.w*b4.y; acc[3][2] += a4.w*b4.z; acc[3][3] += a4.w*b4.w;
    }
    __syncthreads();
  }
  #pragma unroll
  for (int i = 0; i < 4; i++){
    float4 o = make_float4(acc[i][0], acc[i][1], acc[i][2], acc[i][3]);
    *(float4*)(fva + ((size_t)(b * NN + n0 + ty * 4 + i)) * NC + tx * 4) = o;
  }
}

// ---- Mt[b,m,n] = M[b,n,m]
__global__ __launch_bounds__(256) void k_transpose(const float* __restrict__ Mb,
                                                   float* __restrict__ Mt){
  __shared__ float T[64][68];
  int b = blockIdx.z; int n0 = blockIdx.y * 64, m0 = blockIdx.x * 64;
  const float* src = Mb + (size_t)b * NN * NN;
  float* dst = Mt + (size_t)b * NN * NN;
  int tid = threadIdx.x;
  #pragma unroll
  for (int i = 0; i < 4; i++){
    int t = tid + 256 * i; int r = t >> 4, c4 = t & 15;
    float4 v = *(const float4*)(src + (size_t)(n0 + r) * NN + m0 + c4 * 4);
    T[r][c4*4+0] = v.x; T[r][c4*4+1] = v.y; T[r][c4*4+2] = v.z; T[r][c4*4+3] = v.w;
  }
  __syncthreads();
  #pragma unroll
  for (int i = 0; i < 4; i++){
    int t = tid + 256 * i; int r = t >> 4, c4 = t & 15;  // r = m-row of Mt
    float4 v = make_float4(T[c4*4+0][r], T[c4*4+1][r], T[c4*4+2][r], T[c4*4+3][r]);
    *(float4*)(dst + (size_t)(m0 + r) * NN + n0 + c4 * 4) = v;
  }
}

// ---- one sinkhorn half-pass: out[b,i] = -LSE_j(buf[b,i,j]*INV_TAU + vec[b,j])
__global__ void k_lse_pass(const float* __restrict__ buf, const float* __restrict__ vec,
                           float* __restrict__ out){
  int row = blockIdx.x * 4 + (threadIdx.x >> 6);
  int lane = threadIdx.x & 63;
  int b = row >> 10;
  const float* p = buf + (size_t)row * NN;
  const float* vb = vec + (size_t)b * NN;
  float x[16]; float mx = -3.402823466e38f;
  #pragma unroll
  for (int k = 0; k < 16; k++){
    x[k] = fmaf(p[lane + 64 * k], INV_TAU, vb[lane + 64 * k]);
    mx = fmaxf(mx, x[k]);
  }
  mx = wmax(mx);
  float s = 0.0f;
  #pragma unroll
  for (int k = 0; k < 16; k++) s += expf(x[k] - mx);
  s = wsum(s);
  if (lane == 0) out[row] = -(mx + logf(s));
}

// ---- fused final reduction: loss, Lc, perm_to_I
__global__ __launch_bounds__(256) void k_final(const float* __restrict__ Mb,
                                               const float* __restrict__ C12,
                                               const float* __restrict__ lse2,
                                               const float* __restrict__ lse12,
                                               const float* __restrict__ u,
                                               const float* __restrict__ v,
                                               const float* __restrict__ pc0,
                                               float* __restrict__ accs){
  __shared__ float pcs[3072];
  __shared__ float partial[3][4];
  int b = blockIdx.x >> 8;           // 256 blocks per batch
  int tid = threadIdx.x, wid = tid >> 6, lane = tid & 63;
  for (int i = tid; i < 3072; i += 256) pcs[i] = pc0[b * 3072 + i];
  __syncthreads();
  int row = blockIdx.x * 4 + wid;
  int n = row & 1023;
  const float* mrow = Mb + (size_t)row * NN;
  const float* crow = C12 + (size_t)row * NN;
  const float* vb = v + (size_t)b * NN;
  float l2r = lse2[row], l12r = lse12[row], ur = u[row];
  float qx = pcs[n*3], qy = pcs[n*3+1], qz = pcs[n*3+2];
  float sl = 0.0f, slc = 0.0f, spi = 0.0f;
  #pragma unroll 4
  for (int k = 0; k < 16; k++){
    int m = lane + 64 * k;
    float c1 = mrow[m], c2 = crow[m];
    float e1 = expf(c1 - l2r);
    float e2 = expf(c2 - l12r);
    float sk = expf(fmaf(c1, INV_TAU, ur + vb[m]));
    float dx = qx - pcs[m*3], dy = qy - pcs[m*3+1], dz = qz - pcs[m*3+2];
    float d = sqrtf(sqrtf(dx*dx + dy*dy + dz*dz));
    sl  += d * (e1 + e2);
    slc += fabsf(sk - e1);
    spi += fabsf(((m == n) ? 1.0f : 0.0f) - sk);
  }
  sl = wsum(sl); slc = wsum(slc); spi = wsum(spi);
  if (lane == 0){ partial[0][wid] = sl; partial[1][wid] = slc; partial[2][wid] = spi; }
  __syncthreads();
  if (tid < 3){
    float t = partial[tid][0] + partial[tid][1] + partial[tid][2] + partial[tid][3];
    atomicAdd(&accs[tid * 16 + (blockIdx.x & 15)], t);
  }
}

__global__ void k_finalize(const float* __restrict__ accs, float* __restrict__ out){
  if (threadIdx.x == 0){
    float sl = 0, slc = 0, spi = 0, scm = 0;
    for (int j = 0; j < 16; j++){
      sl += accs[j]; slc += accs[16 + j]; spi += accs[32 + j]; scm += accs[48 + j];
    }
    float loss = sl / 1024.0f;
    float Lc   = 3.0f * slc / 1024.0f;
    float perm = 3.0f * spi / 1024.0f;
    float total = loss + Lc;
    out[0] = total / 8.0f;
    out[1] = loss / 8.0f;
    out[2] = Lc / 8.0f;
    out[3] = scm / 8.0f;
    out[4] = perm / 8.0f;
  }
}

extern "C" void kernel_launch(void* const* d_in, const int* in_sizes, int n_in,
                              void* d_out, int out_size, void* d_ws, size_t ws_size,
                              hipStream_t stream){
  const float* feats = (const float*)d_in[0];   // [16,1024,128]
  const float* pc0   = (const float*)d_in[1];   // [8,1024,3]
  float* out = (float*)d_out;                   // 5 scalars

  float* ws  = (float*)d_ws;
  float* f1   = ws;                    // 1,048,576
  float* f2   = f1  + 1048576;         // 1,048,576
  float* fva  = f2  + 1048576;         // 1,048,576
  float* M    = fva + 1048576;         // 8,388,608  (corr_1a -> corr_1a2)
  float* Mt   = M   + 8388608;         // 8,388,608  (corr_1a2^T -> corr_12)
  float* lse1 = Mt  + 8388608;         // 8192
  float* lse2 = lse1 + 8192;           // 8192
  float* lse12= lse2 + 8192;           // 8192
  float* u    = lse12 + 8192;          // 8192
  float* v    = u   + 8192;            // 8192
  float* accs = v   + 8192;            // 64   [loss|lc|perm|cm] x 16 slots
  // total ~79.9 MB
  if (ws_size < (size_t)(accs + 64 - ws) * sizeof(float)) return;

  k_init<<<32, 256, 0, stream>>>(accs, u, v);
  k_normalize<<<16384, 64, 0, stream>>>(feats, f1, f2);
  // corr_1a = f1 @ roll(f1)^T
  k_gemm_bt<<<dim3(16,16,8), 256, 0, stream>>>(f1, f1, M, 1);
  k_rowstats<<<2048, 256, 0, stream>>>(M, lse1);
  // f1_via_fa = softmax(corr_1a) @ roll(f1)
  k_fva<<<dim3(32,8), 256, 0, stream>>>(M, lse1, f1, fva);
  // corr_1a2 = f1_via_fa @ f2^T
  k_gemm_bt<<<dim3(16,16,8), 256, 0, stream>>>(fva, f2, M, 0);
  k_rowstats_argmax<<<2048, 256, 0, stream>>>(M, lse2, accs);
  k_transpose<<<dim3(16,16,8), 256, 0, stream>>>(M, Mt);
  // sinkhorn: la_t = la0 + u[n] + v[m]; 30 x (row pass, col pass)
  for (int it = 0; it < 30; it++){
    k_lse_pass<<<2048, 256, 0, stream>>>(M,  v, u);   // u = -LSE_m(la0 + v)
    k_lse_pass<<<2048, 256, 0, stream>>>(Mt, u, v);   // v = -LSE_n(la0 + u)
  }
  // corr_12 = f1 @ f2^T (reuse Mt)
  k_gemm_bt<<<dim3(16,16,8), 256, 0, stream>>>(f1, f2, Mt, 0);
  k_rowstats<<<2048, 256, 0, stream>>>(Mt, lse12);
  k_final<<<2048, 256, 0, stream>>>(M, Mt, lse2, lse12, u, v, pc0, accs);
  k_finalize<<<1, 64, 0, stream>>>(accs, out);
}

// Round 3
// 727.504 us; speedup vs baseline: 1.0603x; 1.0603x over previous
//
#include <hip/hip_runtime.h>
#include <math.h>

#define NB 8
#define NN 1024
#define NC 128
#define INV_TAU (1.0f/0.3f)

__device__ __forceinline__ float wsum(float v){
  #pragma unroll
  for (int o = 32; o > 0; o >>= 1) v += __shfl_xor(v, o, 64);
  return v;
}
__device__ __forceinline__ float wmax(float v){
  #pragma unroll
  for (int o = 32; o > 0; o >>= 1) v = fmaxf(v, __shfl_xor(v, o, 64));
  return v;
}

// accs layout: [0:16) loss | [16:32) lc | [32:48) perm | [48:64) cm | [64:80) gmax slots | 80 = IQ
__global__ void k_init(float* accs, float* V){
  int i = blockIdx.x * 256 + threadIdx.x;   // grid 32 x 256 = 8192
  if (i < 128) accs[i] = 0.0f;
  V[i] = 0.0f;
}

// ---- L2 normalize * 20 over C; feats[16,1024,128] -> f1 = rows 0::2, f2 = 1::2
__global__ void k_normalize(const float* __restrict__ feats,
                            float* __restrict__ f1, float* __restrict__ f2){
  int vid = blockIdx.x;            // 0..16383 = batch*1024+n
  int lane = threadIdx.x;          // 64 threads, 2 floats each
  const float* src = feats + (size_t)vid * NC;
  float2 x = *(const float2*)(src + lane * 2);
  float s = wsum(x.x * x.x + x.y * x.y);
  float sc = 20.0f / fmaxf(sqrtf(s), 1e-12f);
  int batch = vid >> 10, n = vid & 1023;
  float* dst = ((batch & 1) ? f2 : f1) + ((size_t)(batch >> 1) * NN + n) * NC;
  float2 y; y.x = x.x * sc; y.y = x.y * sc;
  *(float2*)(dst + lane * 2) = y;
}

// ---- C[b] = A[b] (1024x128) * B[(b+rollB)&7]^T -> [1024x1024]
__global__ __launch_bounds__(256) void k_gemm_bt(const float* __restrict__ A,
                                                 const float* __restrict__ Bm,
                                                 float* __restrict__ Cm, int rollB){
  __shared__ float As[64][68];   // [k][row], padded
  __shared__ float Bs[64][68];
  int b = blockIdx.z;
  int n0 = blockIdx.y * 64, m0 = blockIdx.x * 64;
  const float* Ab = A  + (size_t)b * NN * NC;
  const float* Bb = Bm + (size_t)((b + rollB) & 7) * NN * NC;
  float* Cb = Cm + (size_t)b * NN * NN;
  int tid = threadIdx.x;
  int ty = tid >> 4, tx = tid & 15;
  float acc[4][4] = {};
  for (int kk = 0; kk < NC; kk += 64){
    #pragma unroll
    for (int i = 0; i < 4; i++){
      int t = tid + 256 * i;          // 1024 float4 slots
      int r = t >> 4, k4 = t & 15;
      float4 va = *(const float4*)(Ab + (size_t)(n0 + r) * NC + kk + k4 * 4);
      As[k4*4+0][r] = va.x; As[k4*4+1][r] = va.y; As[k4*4+2][r] = va.z; As[k4*4+3][r] = va.w;
      float4 vb = *(const float4*)(Bb + (size_t)(m0 + r) * NC + kk + k4 * 4);
      Bs[k4*4+0][r] = vb.x; Bs[k4*4+1][r] = vb.y; Bs[k4*4+2][r] = vb.z; Bs[k4*4+3][r] = vb.w;
    }
    __syncthreads();
    #pragma unroll 8
    for (int k = 0; k < 64; k++){
      float4 a4 = *(const float4*)&As[k][ty * 4];
      float4 b4 = *(const float4*)&Bs[k][tx * 4];
      acc[0][0] += a4.x*b4.x; acc[0][1] += a4.x*b4.y; acc[0][2] += a4.x*b4.z; acc[0][3] += a4.x*b4.w;
      acc[1][0] += a4.y*b4.x; acc[1][1] += a4.y*b4.y; acc[1][2] += a4.y*b4.z; acc[1][3] += a4.y*b4.w;
      acc[2][0] += a4.z*b4.x; acc[2][1] += a4.z*b4.y; acc[2][2] += a4.z*b4.z; acc[2][3] += a4.z*b4.w;
      acc[3][0] += a4.w*b4.x; acc[3][1] += a4.w*b4.y; acc[3][2] += a4.w*b4.z; acc[3][3] += a4.w*b4.w;
    }
    __syncthreads();
  }
  #pragma unroll
  for (int i = 0; i < 4; i++){
    float4 o = make_float4(acc[i][0], acc[i][1], acc[i][2], acc[i][3]);
    *(float4*)(Cb + (size_t)(n0 + ty * 4 + i) * NN + m0 + tx * 4) = o;
  }
}

// ---- per-row logsumexp: lse = max + log(sum exp(x-max))
__global__ void k_rowstats(const float* __restrict__ Mb, float* __restrict__ lse){
  int row = blockIdx.x * 4 + (threadIdx.x >> 6);
  int lane = threadIdx.x & 63;
  const float* p = Mb + (size_t)row * NN;
  float x[16]; float mx = -3.402823466e38f;
  #pragma unroll
  for (int k = 0; k < 16; k++){ x[k] = p[lane + 64 * k]; mx = fmaxf(mx, x[k]); }
  mx = wmax(mx);
  float s = 0.0f;
  #pragma unroll
  for (int k = 0; k < 16; k++) s += expf(x[k] - mx);
  s = wsum(s);
  if (lane == 0) lse[row] = mx + logf(s);
}

// ---- row stats + argmax + correct_match + global absmax (for int16 scale)
__global__ void k_rowstats_argmax(const float* __restrict__ Mb, float* __restrict__ lse,
                                  float* __restrict__ accs){
  __shared__ float axs[4];
  int row = blockIdx.x * 4 + (threadIdx.x >> 6);
  int wid = threadIdx.x >> 6;
  int lane = threadIdx.x & 63;
  const float* p = Mb + (size_t)row * NN;
  float x[16]; float mx = -3.402823466e38f; float ax = 0.0f;
  float bm = -3.402823466e38f; int bi = 0;
  #pragma unroll
  for (int k = 0; k < 16; k++){
    x[k] = p[lane + 64 * k];
    mx = fmaxf(mx, x[k]);
    ax = fmaxf(ax, fabsf(x[k]));
    if (x[k] > bm){ bm = x[k]; bi = lane + 64 * k; }
  }
  mx = wmax(mx); ax = wmax(ax);
  #pragma unroll
  for (int o = 32; o > 0; o >>= 1){
    float om = __shfl_xor(bm, o, 64); int oi = __shfl_xor(bi, o, 64);
    if (om > bm || (om == bm && oi < bi)){ bm = om; bi = oi; }
  }
  float s = 0.0f;
  #pragma unroll
  for (int k = 0; k < 16; k++) s += expf(x[k] - mx);
  s = wsum(s);
  if (lane == 0){
    lse[row] = mx + logf(s);
    axs[wid] = ax;
    if (bi == (row & 1023)) atomicAdd(&accs[48 + (blockIdx.x & 15)], 1.0f);
  }
  __syncthreads();
  if (threadIdx.x == 0){
    float a = fmaxf(fmaxf(axs[0], axs[1]), fmaxf(axs[2], axs[3]));
    atomicMax((int*)&accs[64 + (blockIdx.x & 15)], __float_as_int(a));  // a >= 0: int cmp == float cmp
  }
}

// ---- finalize quantization scale: IQ = dequant step for L = M/tau
__global__ void k_scale(float* accs){
  if (threadIdx.x == 0){
    float g = 0.0f;
    for (int j = 0; j < 16; j++) g = fmaxf(g, accs[64 + j]);
    accs[80] = (g * INV_TAU) / 32766.0f;   // IQ
  }
}

// ---- fva[b,n,c] = sum_m exp(M[b,n,m]-lse1[b,n]) * f1[(b+1)&7][m][c]
__global__ __launch_bounds__(256) void k_fva(const float* __restrict__ Mb,
                                             const float* __restrict__ lse1,
                                             const float* __restrict__ f1,
                                             float* __restrict__ fva){
  __shared__ float Ps[64][36];    // [m][row(n)], 32 rows
  __shared__ float Bs[64][128];   // [m][c]
  int b = blockIdx.y;
  int n0 = blockIdx.x * 32;
  const float* Mrow = Mb + (size_t)(b * NN + n0) * NN;
  const float* fa = f1 + (size_t)((b + 1) & 7) * NN * NC;
  const float* lseb = lse1 + b * NN + n0;
  int tid = threadIdx.x;
  int ty = tid >> 5, tx = tid & 31;
  float acc[4][4] = {};
  for (int mm = 0; mm < NN; mm += 64){
    #pragma unroll
    for (int i = 0; i < 2; i++){
      int t = tid + 256 * i;        // 512 float4 = 32 rows x 64 m
      int r = t >> 4, m4 = t & 15;
      float l = lseb[r];
      float4 v = *(const float4*)(Mrow + (size_t)r * NN + mm + m4 * 4);
      Ps[m4*4+0][r] = expf(v.x - l); Ps[m4*4+1][r] = expf(v.y - l);
      Ps[m4*4+2][r] = expf(v.z - l); Ps[m4*4+3][r] = expf(v.w - l);
    }
    #pragma unroll
    for (int i = 0; i < 8; i++){
      int t = tid + 256 * i;        // 2048 float4 = 64 m x 128 c
      int m = t >> 5, c4 = t & 31;
      *(float4*)&Bs[m][c4 * 4] = *(const float4*)(fa + (size_t)(mm + m) * NC + c4 * 4);
    }
    __syncthreads();
    #pragma unroll 8
    for (int m = 0; m < 64; m++){
      float4 a4 = *(const float4*)&Ps[m][ty * 4];
      float4 b4 = *(const float4*)&Bs[m][tx * 4];
      acc[0][0] += a4.x*b4.x; acc[0][1] += a4.x*b4.y; acc[0][2] += a4.x*b4.z; acc[0][3] += a4.x*b4.w;
      acc[1][0] += a4.y*b4.x; acc[1][1] += a4.y*b4.y; acc[1][2] += a4.y*b4.z; acc[1][3] += a4.y*b4.w;
      acc[2][0] += a4.z*b4.x; acc[2][1] += a4.z*b4.y; acc[2][2] += a4.z*b4.z; acc[2][3] += a4.z*b4.w;
      acc[3][0] += a4.w*b4.x; acc[3][1] += a4.w*b4.y; acc[3][2] += a4.w*b4.z; acc[3][3] += a4.w*b4.w;
    }
    __syncthreads();
  }
  #pragma unroll
  for (int i = 0; i < 4; i++){
    float4 o = make_float4(acc[i][0], acc[i][1], acc[i][2], acc[i][3]);
    *(float4*)(fva + ((size_t)(b * NN + n0 + ty * 4 + i)) * NC + tx * 4) = o;
  }
}

// ---- quantize L = M/tau to int16 (q = rint(L/IQ)) + transposed copy
__global__ __launch_bounds__(256) void k_quant_t(const float* __restrict__ Mb,
                                                 const float* __restrict__ accs,
                                                 short* __restrict__ Q,
                                                 short* __restrict__ Qt){
  __shared__ float T[64][68];
  float QS = 1.0f / accs[80];
  int b = blockIdx.z; int n0 = blockIdx.y * 64, m0 = blockIdx.x * 64;
  const float* src = Mb + (size_t)b * NN * NN;
  int tid = threadIdx.x;
  #pragma unroll
  for (int i = 0; i < 4; i++){
    int t = tid + 256 * i; int r = t >> 4, c4 = t & 15;
    float4 v = *(const float4*)(src + (size_t)(n0 + r) * NN + m0 + c4 * 4);
    float q0 = rintf(v.x * INV_TAU * QS);
    float q1 = rintf(v.y * INV_TAU * QS);
    float q2 = rintf(v.z * INV_TAU * QS);
    float q3 = rintf(v.w * INV_TAU * QS);
    T[r][c4*4+0] = q0; T[r][c4*4+1] = q1; T[r][c4*4+2] = q2; T[r][c4*4+3] = q3;
    int2 w;
    w.x = ((int)q0 & 0xFFFF) | ((int)q1 << 16);
    w.y = ((int)q2 & 0xFFFF) | ((int)q3 << 16);
    *(int2*)(Q + ((size_t)(b * NN + n0 + r) * NN + m0 + c4 * 4)) = w;
  }
  __syncthreads();
  #pragma unroll
  for (int i = 0; i < 4; i++){
    int t = tid + 256 * i; int r = t >> 4, c4 = t & 15;  // r = m-row of Qt
    float q0 = T[c4*4+0][r], q1 = T[c4*4+1][r], q2 = T[c4*4+2][r], q3 = T[c4*4+3][r];
    int2 w;
    w.x = ((int)q0 & 0xFFFF) | ((int)q1 << 16);
    w.y = ((int)q2 & 0xFFFF) | ((int)q3 << 16);
    *(int2*)(Qt + ((size_t)(b * NN + m0 + r) * NN + n0 + c4 * 4)) = w;
  }
}

// ---- sinkhorn half-pass (robust, per-row max): out[i] = -LSE_j(q[i,j]*IQ + in[j])
__global__ void k_pass(const short* __restrict__ Q, const float* __restrict__ invec,
                       float* __restrict__ outvec, const float* __restrict__ accs){
  float IQ = accs[80];
  int row = blockIdx.x * 4 + (threadIdx.x >> 6);
  int lane = threadIdx.x & 63;
  int b = row >> 10;
  const int* p = (const int*)(Q + (size_t)row * NN);   // 512 packed pairs
  const float* vb = invec + (size_t)b * NN;
  float x[16]; float mx = -3.402823466e38f;
  #pragma unroll
  for (int k = 0; k < 8; k++){
    int j = lane + 64 * k;
    int w = p[j];
    float2 vv = *(const float2*)(vb + 2 * j);
    x[2*k]   = fmaf((float)(short)(w),   IQ, vv.x);
    x[2*k+1] = fmaf((float)(w >> 16),    IQ, vv.y);
    mx = fmaxf(mx, fmaxf(x[2*k], x[2*k+1]));
  }
  mx = wmax(mx);
  float s = 0.0f;
  #pragma unroll
  for (int k = 0; k < 16; k++) s += expf(x[k] - mx);
  s = wsum(s);
  if (lane == 0) outvec[row] = -(mx + logf(s));
}

// ---- fused final reduction: loss, Lc, perm_to_I
// e1 = exp(0.3*L - lse2); sk = exp(L + P[i] + V[j]); e2 = exp(c12 - lse12)
__global__ __launch_bounds__(256) void k_final(const short* __restrict__ Q,
                                               const float* __restrict__ C12,
                                               const float* __restrict__ lse2,
                                               const float* __restrict__ lse12,
                                               const float* __restrict__ P,
                                               const float* __restrict__ V,
                                               const float* __restrict__ pc0,
                                               float* __restrict__ accs){
  __shared__ float pcs[3072];
  __shared__ float partial[3][4];
  float IQ = accs[80];
  int b = blockIdx.x >> 8;           // 256 blocks per batch
  int tid = threadIdx.x, wid = tid >> 6, lane = tid & 63;
  for (int i = tid; i < 3072; i += 256) pcs[i] = pc0[b * 3072 + i];
  __syncthreads();
  int row = blockIdx.x * 4 + wid;
  int n = row & 1023;
  const short* qp = Q + (size_t)row * NN;
  const float* crow = C12 + (size_t)row * NN;
  const float* Vb = V + (size_t)b * NN;
  float l12r = lse12[row];
  float c1row = -lse2[row];
  float Prow = P[row];
  float qx = pcs[n*3], qy = pcs[n*3+1], qz = pcs[n*3+2];
  float sl = 0.0f, slc = 0.0f, spi = 0.0f;
  #pragma unroll
  for (int k = 0; k < 4; k++){
    int j0 = 4 * lane + 256 * k;
    int2 qw = *(const int2*)(qp + j0);
    float4 c2 = *(const float4*)(crow + j0);
    float4 v4 = *(const float4*)(Vb + j0);
    float L[4] = { (float)(short)(qw.x) * IQ, (float)(qw.x >> 16) * IQ,
                   (float)(short)(qw.y) * IQ, (float)(qw.y >> 16) * IQ };
    float cc[4] = { c2.x, c2.y, c2.z, c2.w };
    float vv[4] = { v4.x, v4.y, v4.z, v4.w };
    #pragma unroll
    for (int q = 0; q < 4; q++){
      int m = j0 + q;
      float e1 = expf(fmaf(L[q], 0.3f, c1row));
      float sk = expf(L[q] + Prow + vv[q]);
      float e2v = expf(cc[q] - l12r);
      float dx = qx - pcs[m*3], dy = qy - pcs[m*3+1], dz = qz - pcs[m*3+2];
      float d = sqrtf(sqrtf(dx*dx + dy*dy + dz*dz));
      sl  += d * (e1 + e2v);
      slc += fabsf(sk - e1);
      spi += fabsf(((m == n) ? 1.0f : 0.0f) - sk);
    }
  }
  sl = wsum(sl); slc = wsum(slc); spi = wsum(spi);
  if (lane == 0){ partial[0][wid] = sl; partial[1][wid] = slc; partial[2][wid] = spi; }
  __syncthreads();
  if (tid < 3){
    float t = partial[tid][0] + partial[tid][1] + partial[tid][2] + partial[tid][3];
    atomicAdd(&accs[tid * 16 + (blockIdx.x & 15)], t);
  }
}

__global__ void k_finalize(const float* __restrict__ accs, float* __restrict__ out){
  if (threadIdx.x == 0){
    float sl = 0, slc = 0, spi = 0, scm = 0;
    for (int j = 0; j < 16; j++){
      sl += accs[j]; slc += accs[16 + j]; spi += accs[32 + j]; scm += accs[48 + j];
    }
    float loss = sl / 1024.0f;
    float Lc   = 3.0f * slc / 1024.0f;
    float perm = 3.0f * spi / 1024.0f;
    float total = loss + Lc;
    out[0] = total / 8.0f;
    out[1] = loss / 8.0f;
    out[2] = Lc / 8.0f;
    out[3] = scm / 8.0f;
    out[4] = perm / 8.0f;
  }
}

extern "C" void kernel_launch(void* const* d_in, const int* in_sizes, int n_in,
                              void* d_out, int out_size, void* d_ws, size_t ws_size,
                              hipStream_t stream){
  const float* feats = (const float*)d_in[0];   // [16,1024,128]
  const float* pc0   = (const float*)d_in[1];   // [8,1024,3]
  float* out = (float*)d_out;                   // 5 scalars

  float* ws  = (float*)d_ws;
  float* f1   = ws;                    // 1,048,576 f
  float* f2   = f1  + 1048576;         // 1,048,576 f
  float* fva  = f2  + 1048576;         // 1,048,576 f
  float* M    = fva + 1048576;         // 8,388,608 f : corr_1a -> corr_1a2 -> corr_12
  short* Q    = (short*)(M + 8388608); // 8,388,608 s16 (= 4,194,304 f)
  short* Qt   = Q + 8388608;           // 8,388,608 s16
  float* lse1 = (float*)(Qt + 8388608);// 8192
  float* lse2 = lse1 + 8192;           // 8192
  float* lse12= lse2 + 8192;           // 8192
  float* P    = lse12 + 8192;          // 8192
  float* V    = P   + 8192;            // 8192
  float* accs = V   + 8192;            // 128
  if (ws_size < (size_t)((float*)(accs + 128) - ws) * sizeof(float)) return;

  k_init<<<32, 256, 0, stream>>>(accs, V);
  k_normalize<<<16384, 64, 0, stream>>>(feats, f1, f2);
  // corr_1a = f1 @ roll(f1)^T
  k_gemm_bt<<<dim3(16,16,8), 256, 0, stream>>>(f1, f1, M, 1);
  k_rowstats<<<2048, 256, 0, stream>>>(M, lse1);
  // f1_via_fa = softmax(corr_1a) @ roll(f1)
  k_fva<<<dim3(32,8), 256, 0, stream>>>(M, lse1, f1, fva);
  // corr_1a2 = f1_via_fa @ f2^T
  k_gemm_bt<<<dim3(16,16,8), 256, 0, stream>>>(fva, f2, M, 0);
  k_rowstats_argmax<<<2048, 256, 0, stream>>>(M, lse2, accs);
  k_scale<<<1, 64, 0, stream>>>(accs);
  // Q = int16(M/tau), Qt = transpose
  k_quant_t<<<dim3(16,16,8), 256, 0, stream>>>(M, accs, Q, Qt);
  // corr_12 = f1 @ f2^T (reuses M buffer — safe, Q/Qt captured)
  k_gemm_bt<<<dim3(16,16,8), 256, 0, stream>>>(f1, f2, M, 0);
  k_rowstats<<<2048, 256, 0, stream>>>(M, lse12);
  // sinkhorn on quantized L: P[i] = -LSE_j(L+V), V[j] = -LSE_i(L^T+P), 30 iters
  for (int it = 0; it < 30; it++){
    k_pass<<<2048, 256, 0, stream>>>(Q,  V, P, accs);
    k_pass<<<2048, 256, 0, stream>>>(Qt, P, V, accs);
  }
  k_final<<<2048, 256, 0, stream>>>(Q, M, lse2, lse12, P, V, pc0, accs);
  k_finalize<<<1, 64, 0, stream>>>(accs, out);
}